// Round 4
// baseline (391.635 us; speedup 1.0000x reference)
//
#include <hip/hip_runtime.h>
#include <cstdint>

typedef short short8 __attribute__((ext_vector_type(8)));
typedef float f32x4  __attribute__((ext_vector_type(4)));

// RNE float -> bf16 hi + bf16 lo split (scalar, for the tiny W prep kernel)
__device__ __forceinline__ void split2(float x, short& h, short& l) {
  unsigned u  = __float_as_uint(x);
  unsigned rh = u + 0x7FFFu + ((u >> 16) & 1u);
  h = (short)(rh >> 16);
  float hf = __uint_as_float((rh >> 16) << 16);
  float lf = x - hf;
  unsigned ul = __float_as_uint(lf);
  unsigned rl = ul + 0x7FFFu + ((ul >> 16) & 1u);
  l = (short)(rl >> 16);
}

// ---------------------------------------------------------------------------
// head[i] = -1  (replaces hipMemsetAsync: runtime fillBuffer took 146us!)
// ---------------------------------------------------------------------------
__global__ __launch_bounds__(256) void init_head(int* __restrict__ head, int N)
{
  const int i = blockIdx.x * 256 + threadIdx.x;
  if (i < N) head[i] = -1;
}

// ---------------------------------------------------------------------------
// Pre-convert all 5 GEMM weight matrices [K][64] f32 -> bf16 hi/lo in MFMA
// B-fragment order. Segment k-row layout (padded to mult. of 32):
//   Wi:512  Wt:768  Wn:16->32  Wc:8->32  Wf:256   (total 1600 padded k-rows)
// ---------------------------------------------------------------------------
__global__ __launch_bounds__(256) void prep_w(
    const float* __restrict__ Wi, const float* __restrict__ Wt,
    const float* __restrict__ Wn, const float* __restrict__ Wc,
    const float* __restrict__ Wf, short* __restrict__ hi, short* __restrict__ lo)
{
  int idx = blockIdx.x * 256 + threadIdx.x;
  if (idx >= 1600 * 64) return;
  int kp = idx >> 6, col = idx & 63;
  const float* W; int K, kloc, base;
  if (kp < 512)       { W = Wi; K = 512; kloc = kp;        base = 0;    }
  else if (kp < 1280) { W = Wt; K = 768; kloc = kp - 512;  base = 512;  }
  else if (kp < 1312) { W = Wn; K = 16;  kloc = kp - 1280; base = 1280; }
  else if (kp < 1344) { W = Wc; K = 8;   kloc = kp - 1312; base = 1312; }
  else                { W = Wf; K = 256; kloc = kp - 1344; base = 1344; }
  float x = (kloc < K) ? W[(size_t)kloc * 64 + col] : 0.f;
  short h, l; split2(x, h, l);
  int s = kloc >> 5;
  int addr = ((s * 4 + (col >> 4)) * 64 + ((col & 15) | (((kloc >> 3) & 3) << 4))) * 8 + (kloc & 7);
  size_t o = (size_t)base * 64 + addr;
  hi[o] = h; lo[o] = l;
}

// ---------------------------------------------------------------------------
// C[m,0:64] = relu(A[m,0:K] @ W + bias) via bf16 hi/lo split MFMA (3 products)
// block = 256 = 4 waves; tile = 64 rows x 64 cols; K-step = 32, dbuf LDS.
// ---------------------------------------------------------------------------
__global__ __launch_bounds__(256) void gemm_mfma_relu(
    const float* __restrict__ A, int lda, int K, int ksteps,
    const short* __restrict__ Whi, const short* __restrict__ Wlo,
    const float* __restrict__ bias, float* __restrict__ C, int ldc, int M)
{
  __shared__ short Ahi[2][2048];
  __shared__ short Alo[2][2048];
  const int tid = threadIdx.x;
  const int m0  = blockIdx.x * 64;
  const int w   = tid >> 6, l = tid & 63;

  f32x4 acc[4];
#pragma unroll
  for (int n = 0; n < 4; n++) acc[n] = (f32x4){0.f, 0.f, 0.f, 0.f};

  const int srow = tid >> 3;        // 0..31 (handles srow and srow+32)
  const int k0   = (tid & 7) * 4;   // 0,4,...,28
  const int i0   = k0 & 7;          // 0 or 4
  const int kg   = k0 >> 3;         // 0..3

  auto stage = [&](int s, int buf) {
#pragma unroll
    for (int r2 = 0; r2 < 2; r2++) {
      const int row  = srow + r2 * 32;
      const int grow = m0 + row;
      const int k    = s * 32 + k0;
      float4 a = make_float4(0.f, 0.f, 0.f, 0.f);
      if (grow < M && k < K)
        a = *reinterpret_cast<const float4*>(A + (size_t)grow * lda + k);
      unsigned hp0, hp1, lp0, lp1;
      asm("v_cvt_pk_bf16_f32 %0, %1, %2" : "=v"(hp0) : "v"(a.x), "v"(a.y));
      asm("v_cvt_pk_bf16_f32 %0, %1, %2" : "=v"(hp1) : "v"(a.z), "v"(a.w));
      float h0 = __uint_as_float(hp0 << 16);
      float h1 = __uint_as_float(hp0 & 0xFFFF0000u);
      float h2 = __uint_as_float(hp1 << 16);
      float h3 = __uint_as_float(hp1 & 0xFFFF0000u);
      float l0 = a.x - h0, l1 = a.y - h1, l2 = a.z - h2, l3 = a.w - h3;
      asm("v_cvt_pk_bf16_f32 %0, %1, %2" : "=v"(lp0) : "v"(l0), "v"(l1));
      asm("v_cvt_pk_bf16_f32 %0, %1, %2" : "=v"(lp1) : "v"(l2), "v"(l3));
      const int addr = (row >> 4) * 512 + (((row & 15) | (kg << 4)) * 8 + i0);
      *reinterpret_cast<uint2*>(&Ahi[buf][addr]) = make_uint2(hp0, hp1);
      *reinterpret_cast<uint2*>(&Alo[buf][addr]) = make_uint2(lp0, lp1);
    }
  };

  stage(0, 0);
  for (int s = 0; s < ksteps; s++) {
    __syncthreads();
    if (s + 1 < ksteps) stage(s + 1, (s + 1) & 1);
    const int buf = s & 1;
    short8 ahi = *reinterpret_cast<const short8*>(&Ahi[buf][w * 512 + l * 8]);
    short8 alo = *reinterpret_cast<const short8*>(&Alo[buf][w * 512 + l * 8]);
#pragma unroll
    for (int n = 0; n < 4; n++) {
      short8 whi = *reinterpret_cast<const short8*>(&Whi[((size_t)(s * 4 + n)) * 512 + l * 8]);
      short8 wlo = *reinterpret_cast<const short8*>(&Wlo[((size_t)(s * 4 + n)) * 512 + l * 8]);
      acc[n] = __builtin_amdgcn_mfma_f32_16x16x32_bf16(ahi, whi, acc[n], 0, 0, 0);
      acc[n] = __builtin_amdgcn_mfma_f32_16x16x32_bf16(alo, whi, acc[n], 0, 0, 0);
      acc[n] = __builtin_amdgcn_mfma_f32_16x16x32_bf16(ahi, wlo, acc[n], 0, 0, 0);
    }
  }

  // D layout: col = lane&15, row = (lane>>4)*4 + reg
  const int rb  = m0 + w * 16 + (l >> 4) * 4;
  const int c15 = l & 15;
#pragma unroll
  for (int n = 0; n < 4; n++) {
    const int c = n * 16 + c15;
    const float bb = bias[c];
#pragma unroll
    for (int j = 0; j < 4; j++) {
      const int r = rb + j;
      if (r < M) C[(size_t)r * ldc + c] = fmaxf(acc[n][j] + bb, 0.f);
    }
  }
}

// ---------------------------------------------------------------------------
// Tab[r,0:64] = relu(nf[r/3] + Eet[r%3, eoff:+64]) @ Wm1half (+ bias if given)
// ---------------------------------------------------------------------------
__global__ __launch_bounds__(256) void build_table(
    const float* __restrict__ nf, const float* __restrict__ Eet, int eoff,
    const float* __restrict__ Wm1half, const float* __restrict__ bias,
    float* __restrict__ Tab, int N3)
{
  __shared__ float Es[64][68];
  __shared__ float Ws[64][68];
  const int tid = threadIdx.x;
  const int m0  = blockIdx.x * 64;
  const int ty  = tid >> 4, tx = tid & 15;

  {
    const int r = tid >> 2;
    const int rg = m0 + r;
    const int n = rg / 3;
    const int t = rg - n * 3;
#pragma unroll
    for (int j = 0; j < 4; j++) {
      const int k0 = (tid & 3) * 4 + j * 16;
      float4 v = make_float4(0.f, 0.f, 0.f, 0.f);
      if (rg < N3) {
        float4 x = *reinterpret_cast<const float4*>(nf + (size_t)n * 64 + k0);
        float4 e = *reinterpret_cast<const float4*>(Eet + (size_t)t * 128 + eoff + k0);
        v.x = fmaxf(x.x + e.x, 0.f); v.y = fmaxf(x.y + e.y, 0.f);
        v.z = fmaxf(x.z + e.z, 0.f); v.w = fmaxf(x.w + e.w, 0.f);
      }
      Es[k0 + 0][r] = v.x; Es[k0 + 1][r] = v.y;
      Es[k0 + 2][r] = v.z; Es[k0 + 3][r] = v.w;
    }
  }
  {
    const int kr = tid >> 4, c0 = (tid & 15) * 4;
#pragma unroll
    for (int j = 0; j < 4; j++) {
      const int k = kr + j * 16;
      *reinterpret_cast<float4*>(&Ws[k][c0]) =
          *reinterpret_cast<const float4*>(Wm1half + (size_t)k * 64 + c0);
    }
  }
  __syncthreads();

  float acc[4][4];
#pragma unroll
  for (int i = 0; i < 4; i++)
#pragma unroll
    for (int j = 0; j < 4; j++) acc[i][j] = 0.f;

#pragma unroll 16
  for (int kk = 0; kk < 64; kk++) {
    float4 a = *reinterpret_cast<const float4*>(&Es[kk][ty * 4]);
    float4 w = *reinterpret_cast<const float4*>(&Ws[kk][tx * 4]);
    float av[4] = {a.x, a.y, a.z, a.w};
    float wv[4] = {w.x, w.y, w.z, w.w};
#pragma unroll
    for (int i = 0; i < 4; i++)
#pragma unroll
      for (int j = 0; j < 4; j++)
        acc[i][j] = fmaf(av[i], wv[j], acc[i][j]);
  }

  float4 bv = make_float4(0.f, 0.f, 0.f, 0.f);
  if (bias) bv = *reinterpret_cast<const float4*>(bias + tx * 4);
#pragma unroll
  for (int i = 0; i < 4; i++) {
    const int row = m0 + ty * 4 + i;
    if (row < N3) {
      float4 o = make_float4(acc[i][0] + bv.x, acc[i][1] + bv.y,
                             acc[i][2] + bv.z, acc[i][3] + bv.w);
      *reinterpret_cast<float4*>(Tab + (size_t)row * 64 + tx * 4) = o;
    }
  }
}

// ---------------------------------------------------------------------------
// 16 lanes per edge (16 edges per block): logits -> sigmoid -> Bernoulli ->
// trusted edges appended to per-src linked list (4B atomicExch + 4B store).
// bm1 is pre-folded into Atab.  NO float atomics.
// ---------------------------------------------------------------------------
__global__ __launch_bounds__(256) void edge_kernel(
    const int* __restrict__ ei, const int* __restrict__ et,
    const float* __restrict__ u,
    const float* __restrict__ Atab, const float* __restrict__ Btab,
    const float* __restrict__ Wm2, const float* __restrict__ bm2,
    int* __restrict__ head, int* __restrict__ nxt, int E)
{
  const int tid = threadIdx.x;
  const int e   = blockIdx.x * 16 + (tid >> 4);
  const int sub = tid & 15;
  if (e >= E) return;

  const int sn = ei[e];
  const int dn = ei[E + e];
  const int t  = et[e];

  float4 a  = *reinterpret_cast<const float4*>(Atab + ((size_t)sn * 3 + t) * 64 + sub * 4);
  float4 b  = *reinterpret_cast<const float4*>(Btab + ((size_t)dn * 3 + t) * 64 + sub * 4);
  float4 wv = *reinterpret_cast<const float4*>(Wm2 + sub * 4);

  float v = fmaxf(a.x + b.x, 0.f) * wv.x;
  v = fmaf(fmaxf(a.y + b.y, 0.f), wv.y, v);
  v = fmaf(fmaxf(a.z + b.z, 0.f), wv.z, v);
  v = fmaf(fmaxf(a.w + b.w, 0.f), wv.w, v);
  v += __shfl_xor(v, 1);
  v += __shfl_xor(v, 2);
  v += __shfl_xor(v, 4);
  v += __shfl_xor(v, 8);

  if (sub == 0) {
    const float p = 1.f / (1.f + expf(-(v + bm2[0])));
    if (u[e] < p) {
      nxt[e] = atomicExch(&head[sn], e);
    }
  }
}

// ---------------------------------------------------------------------------
// one wave per node: walk trusted-edge chain, accumulate nf[dst] rows
// (no atomics, coalesced 256B row reads), then agg @ Wcls + bcls -> out.
// ---------------------------------------------------------------------------
__global__ __launch_bounds__(256) void node_kernel(
    const int* __restrict__ head, const int* __restrict__ nxt,
    const int* __restrict__ ei,
    const float* __restrict__ nf,
    const float* __restrict__ Wcls, const float* __restrict__ bcls,
    float* __restrict__ out, int N, int E)
{
  const int n    = (int)((blockIdx.x * (unsigned)blockDim.x + threadIdx.x) >> 6);
  const int lane = threadIdx.x & 63;
  if (n >= N) return;

  float acc = 0.f;
  int   c   = 0;
  int   e   = head[n];
  while (e >= 0) {
    const int dn = ei[E + e];
    acc += nf[(size_t)dn * 64 + lane];
    c++;
    e = nxt[e];
  }

  const float agg = (c > 0) ? acc / (float)c : nf[(size_t)n * 64 + lane];
  float r0 = agg * Wcls[lane * 2 + 0];
  float r1 = agg * Wcls[lane * 2 + 1];
#pragma unroll
  for (int off = 32; off; off >>= 1) {
    r0 += __shfl_xor(r0, off, 64);
    r1 += __shfl_xor(r1, off, 64);
  }
  if (lane == 0) {
    out[(size_t)n * 2 + 0] = r0 + bcls[0];
    out[(size_t)n * 2 + 1] = r1 + bcls[1];
  }
}

// ---------------------------------------------------------------------------
extern "C" void kernel_launch(void* const* d_in, const int* in_sizes, int n_in,
                              void* d_out, int out_size, void* d_ws, size_t ws_size,
                              hipStream_t stream)
{
  const float* image    = (const float*)d_in[0];
  const float* tweets   = (const float*)d_in[1];
  const float* num_prop = (const float*)d_in[2];
  const float* category = (const float*)d_in[3];
  const int*   ei       = (const int*)  d_in[4];
  const int*   et       = (const int*)  d_in[5];
  // d_in[6] = eps : unused (z is dead code)
  const float* u        = (const float*)d_in[7];
  const float* Wi  = (const float*)d_in[8],  *bi  = (const float*)d_in[9];
  const float* Wt  = (const float*)d_in[10], *bt  = (const float*)d_in[11];
  const float* Wn  = (const float*)d_in[12], *bn  = (const float*)d_in[13];
  const float* Wc  = (const float*)d_in[14], *bc  = (const float*)d_in[15];
  const float* Wf  = (const float*)d_in[16], *bf  = (const float*)d_in[17];
  const float* Eet = (const float*)d_in[18];
  // d_in[19..22] = Wmu,bmu,Wlv,blv : unused (z is dead code)
  const float* Wm1 = (const float*)d_in[23], *bm1 = (const float*)d_in[24];
  const float* Wm2 = (const float*)d_in[25], *bm2 = (const float*)d_in[26];
  const float* Wcls= (const float*)d_in[27], *bcls= (const float*)d_in[28];
  float* out = (float*)d_out;

  const int N = in_sizes[0] / 512;
  const int E = in_sizes[5];

  float* ws = (float*)d_ws;
  size_t off = 0;
  float* concat = ws + off;  off += (size_t)N * 256;
  float* nf     = ws + off;  off += (size_t)N * 64;
  float* Atab   = ws + off;  off += (size_t)N * 3 * 64;
  float* Btab   = ws + off;  off += (size_t)N * 3 * 64;
  int*   head   = (int*)(ws + off);  off += (size_t)N;
  int*   nxt    = (int*)(ws + off);  off += (size_t)E;
  short* Wfhi   = (short*)(ws + off);  off += (1600 * 64) / 2;  // 102400 shorts
  short* Wflo   = (short*)(ws + off);  off += (1600 * 64) / 2;

  init_head<<<(N + 255) / 256, 256, 0, stream>>>(head, N);

  prep_w<<<(1600 * 64 + 255) / 256, 256, 0, stream>>>(Wi, Wt, Wn, Wc, Wf, Wfhi, Wflo);

  const int gN = (N + 63) / 64;
  // segment bases (padded k-rows): Wi:0  Wt:512  Wn:1280  Wc:1312  Wf:1344
  gemm_mfma_relu<<<gN, 256, 0, stream>>>(image,    512, 512, 16, Wfhi + (size_t)0    * 64, Wflo + (size_t)0    * 64, bi, concat + 0,   256, N);
  gemm_mfma_relu<<<gN, 256, 0, stream>>>(tweets,   768, 768, 24, Wfhi + (size_t)512  * 64, Wflo + (size_t)512  * 64, bt, concat + 64,  256, N);
  gemm_mfma_relu<<<gN, 256, 0, stream>>>(num_prop, 16,  16,  1,  Wfhi + (size_t)1280 * 64, Wflo + (size_t)1280 * 64, bn, concat + 128, 256, N);
  gemm_mfma_relu<<<gN, 256, 0, stream>>>(category, 8,   8,   1,  Wfhi + (size_t)1312 * 64, Wflo + (size_t)1312 * 64, bc, concat + 192, 256, N);
  gemm_mfma_relu<<<gN, 256, 0, stream>>>(concat,   256, 256, 8,  Wfhi + (size_t)1344 * 64, Wflo + (size_t)1344 * 64, bf, nf,           64,  N);

  const int N3 = N * 3;
  const int gT = (N3 + 63) / 64;
  build_table<<<gT, 256, 0, stream>>>(nf, Eet, 0,  Wm1,           bm1,     Atab, N3);
  build_table<<<gT, 256, 0, stream>>>(nf, Eet, 64, Wm1 + 64 * 64, nullptr, Btab, N3);

  edge_kernel<<<(E + 15) / 16, 256, 0, stream>>>(ei, et, u, Atab, Btab,
                                                 Wm2, bm2, head, nxt, E);

  node_kernel<<<(N + 3) / 4, 256, 0, stream>>>(head, nxt, ei, nf, Wcls, bcls,
                                               out, N, E);
}

// Round 5
// 328.814 us; speedup vs baseline: 1.1911x; 1.1911x over previous
//
#include <hip/hip_runtime.h>
#include <cstdint>

typedef short short8 __attribute__((ext_vector_type(8)));
typedef float f32x4  __attribute__((ext_vector_type(4)));

// RNE float -> bf16 hi + bf16 lo split (scalar, for the tiny W prep kernel)
__device__ __forceinline__ void split2(float x, short& h, short& l) {
  unsigned u  = __float_as_uint(x);
  unsigned rh = u + 0x7FFFu + ((u >> 16) & 1u);
  h = (short)(rh >> 16);
  float hf = __uint_as_float((rh >> 16) << 16);
  float lf = x - hf;
  unsigned ul = __float_as_uint(lf);
  unsigned rl = ul + 0x7FFFu + ((ul >> 16) & 1u);
  l = (short)(rl >> 16);
}

// float4 -> packed bf16 hi pair + lo pair (vector path, v_cvt_pk_bf16_f32)
__device__ __forceinline__ void split4(float4 a, uint2& hp, uint2& lp) {
  unsigned hp0, hp1, lp0, lp1;
  asm("v_cvt_pk_bf16_f32 %0, %1, %2" : "=v"(hp0) : "v"(a.x), "v"(a.y));
  asm("v_cvt_pk_bf16_f32 %0, %1, %2" : "=v"(hp1) : "v"(a.z), "v"(a.w));
  float h0 = __uint_as_float(hp0 << 16);
  float h1 = __uint_as_float(hp0 & 0xFFFF0000u);
  float h2 = __uint_as_float(hp1 << 16);
  float h3 = __uint_as_float(hp1 & 0xFFFF0000u);
  float l0 = a.x - h0, l1 = a.y - h1, l2 = a.z - h2, l3 = a.w - h3;
  asm("v_cvt_pk_bf16_f32 %0, %1, %2" : "=v"(lp0) : "v"(l0), "v"(l1));
  asm("v_cvt_pk_bf16_f32 %0, %1, %2" : "=v"(lp1) : "v"(l2), "v"(l3));
  hp = make_uint2(hp0, hp1);
  lp = make_uint2(lp0, lp1);
}

// ---------------------------------------------------------------------------
// head[i] = -1
// ---------------------------------------------------------------------------
__global__ __launch_bounds__(256) void init_head(int* __restrict__ head, int N)
{
  const int i = blockIdx.x * 256 + threadIdx.x;
  if (i < N) head[i] = -1;
}

// ---------------------------------------------------------------------------
// Pre-convert all weight matrices [K][64] f32 -> bf16 hi/lo in MFMA B-frag
// order. k-row segments (padded to mult of 32):
//   Wi:0(512)  Wt:512(768)  Wn:1280(32,K=16)  Wc:1312(32,K=8)  Wf:1344(256)
//   Wm1A:1600(64)  Wm1B:1664(64)     total 1728 k-rows
// step index = k-row/32:  Wi:0..15 Wt:16..39 Wn:40 Wc:41 Wf:42..49
//   Wm1A:50..51 Wm1B:52..53
// ---------------------------------------------------------------------------
__global__ __launch_bounds__(256) void prep_w(
    const float* __restrict__ Wi, const float* __restrict__ Wt,
    const float* __restrict__ Wn, const float* __restrict__ Wc,
    const float* __restrict__ Wf, const float* __restrict__ Wm1,
    short* __restrict__ hi, short* __restrict__ lo)
{
  int idx = blockIdx.x * 256 + threadIdx.x;
  if (idx >= 1728 * 64) return;
  int kp = idx >> 6, col = idx & 63;
  const float* W; int K, kloc, base;
  if (kp < 512)       { W = Wi;            K = 512; kloc = kp;        base = 0;    }
  else if (kp < 1280) { W = Wt;            K = 768; kloc = kp - 512;  base = 512;  }
  else if (kp < 1312) { W = Wn;            K = 16;  kloc = kp - 1280; base = 1280; }
  else if (kp < 1344) { W = Wc;            K = 8;   kloc = kp - 1312; base = 1312; }
  else if (kp < 1600) { W = Wf;            K = 256; kloc = kp - 1344; base = 1344; }
  else if (kp < 1664) { W = Wm1;           K = 64;  kloc = kp - 1600; base = 1600; }
  else                { W = Wm1 + 64 * 64; K = 64;  kloc = kp - 1664; base = 1664; }
  float x = (kloc < K) ? W[(size_t)kloc * 64 + col] : 0.f;
  short h, l; split2(x, h, l);
  int s = kloc >> 5;
  int addr = ((s * 4 + (col >> 4)) * 64 + ((col & 15) | (((kloc >> 3) & 3) << 4))) * 8 + (kloc & 7);
  size_t o = (size_t)base * 64 + addr;
  hi[o] = h; lo[o] = l;
}

// ---------------------------------------------------------------------------
// Fused encoder: nf = relu(concat(relu(x_s @ W_s + b_s)) @ Wf + bf)
// One kernel, 64-row tiles, 4 waves. Stage-1 per segment via hi/lo-split
// MFMA; relu'd 64-col result goes to LDS (f32), is re-split into A-frag
// layout, and feeds stage-2 MFMA against the matching Wf k-block.
// ---------------------------------------------------------------------------
__global__ __launch_bounds__(256) void encoder(
    const float* __restrict__ image, const float* __restrict__ tweets,
    const float* __restrict__ nump, const float* __restrict__ catg,
    const short* __restrict__ Whi, const short* __restrict__ Wlo,
    const float* __restrict__ bi, const float* __restrict__ bt,
    const float* __restrict__ bn, const float* __restrict__ bc,
    const float* __restrict__ bf, float* __restrict__ nf, int M)
{
  __shared__ short Ahi[2][2048];
  __shared__ short Alo[2][2048];
  __shared__ float htile[64 * 68];
  const int tid  = threadIdx.x;
  const int m0   = blockIdx.x * 64;
  const int w    = tid >> 6, l = tid & 63;
  const int srow = tid >> 3;        // 0..31 (handles srow and srow+32)
  const int k0   = (tid & 7) * 4;   // 0,4,...,28
  const int i0   = k0 & 7;          // 0 or 4
  const int kg   = k0 >> 3;         // 0..3

  f32x4 acc2[4];
#pragma unroll
  for (int n = 0; n < 4; n++) acc2[n] = (f32x4){0.f, 0.f, 0.f, 0.f};

  auto stage = [&](const float* A, int lda, int K, int s, int buf) {
#pragma unroll
    for (int r2 = 0; r2 < 2; r2++) {
      const int row  = srow + r2 * 32;
      const int grow = m0 + row;
      const int k    = s * 32 + k0;
      float4 a = make_float4(0.f, 0.f, 0.f, 0.f);
      if (grow < M && k < K) {
        if (k + 3 < K) {
          a = *reinterpret_cast<const float4*>(A + (size_t)grow * lda + k);
        } else {
          a.x = A[(size_t)grow * lda + k];
        }
      }
      uint2 hp, lp; split4(a, hp, lp);
      const int addr = (row >> 4) * 512 + (((row & 15) | (kg << 4)) * 8 + i0);
      *reinterpret_cast<uint2*>(&Ahi[buf][addr]) = hp;
      *reinterpret_cast<uint2*>(&Alo[buf][addr]) = lp;
    }
  };

  auto do_segment = [&](const float* A, int lda, int K, int ksteps,
                        int wstep0, const float* bias, int seg) {
    f32x4 acc[4];
#pragma unroll
    for (int n = 0; n < 4; n++) acc[n] = (f32x4){0.f, 0.f, 0.f, 0.f};

    stage(A, lda, K, 0, 0);
    for (int s = 0; s < ksteps; s++) {
      __syncthreads();
      if (s + 1 < ksteps) stage(A, lda, K, s + 1, (s + 1) & 1);
      const int buf = s & 1;
      short8 ahi = *reinterpret_cast<const short8*>(&Ahi[buf][w * 512 + l * 8]);
      short8 alo = *reinterpret_cast<const short8*>(&Alo[buf][w * 512 + l * 8]);
#pragma unroll
      for (int n = 0; n < 4; n++) {
        short8 whi = *reinterpret_cast<const short8*>(&Whi[((size_t)(wstep0 + s) * 4 + n) * 512 + l * 8]);
        short8 wlo = *reinterpret_cast<const short8*>(&Wlo[((size_t)(wstep0 + s) * 4 + n) * 512 + l * 8]);
        acc[n] = __builtin_amdgcn_mfma_f32_16x16x32_bf16(ahi, whi, acc[n], 0, 0, 0);
        acc[n] = __builtin_amdgcn_mfma_f32_16x16x32_bf16(alo, whi, acc[n], 0, 0, 0);
        acc[n] = __builtin_amdgcn_mfma_f32_16x16x32_bf16(ahi, wlo, acc[n], 0, 0, 0);
      }
    }
    __syncthreads();   // MFMA reads of Ahi done

    // h = relu(acc + bias) -> htile  (D layout: col=lane&15, row=(lane>>4)*4+j)
#pragma unroll
    for (int n = 0; n < 4; n++) {
      const int c  = n * 16 + (l & 15);
      const float bb = bias[c];
#pragma unroll
      for (int j = 0; j < 4; j++) {
        const int row = w * 16 + (l >> 4) * 4 + j;
        htile[row * 68 + c] = fmaxf(acc[n][j] + bb, 0.f);
      }
    }
    __syncthreads();

    // rebuild A-frags from htile (K=64 -> 2 K-steps)
#pragma unroll
    for (int ks2 = 0; ks2 < 2; ks2++) {
#pragma unroll
      for (int r2 = 0; r2 < 2; r2++) {
        const int row = srow + r2 * 32;
        float4 a = *reinterpret_cast<const float4*>(&htile[row * 68 + ks2 * 32 + k0]);
        uint2 hp, lp; split4(a, hp, lp);
        const int addr = (row >> 4) * 512 + (((row & 15) | (kg << 4)) * 8 + i0);
        *reinterpret_cast<uint2*>(&Ahi[ks2][addr]) = hp;
        *reinterpret_cast<uint2*>(&Alo[ks2][addr]) = lp;
      }
    }
    __syncthreads();

    // stage-2 MFMA against Wf k-block of this segment (steps 42+2*seg..+1)
#pragma unroll
    for (int ks2 = 0; ks2 < 2; ks2++) {
      short8 ahi = *reinterpret_cast<const short8*>(&Ahi[ks2][w * 512 + l * 8]);
      short8 alo = *reinterpret_cast<const short8*>(&Alo[ks2][w * 512 + l * 8]);
      const int st = 42 + seg * 2 + ks2;
#pragma unroll
      for (int n = 0; n < 4; n++) {
        short8 whi = *reinterpret_cast<const short8*>(&Whi[((size_t)st * 4 + n) * 512 + l * 8]);
        short8 wlo = *reinterpret_cast<const short8*>(&Wlo[((size_t)st * 4 + n) * 512 + l * 8]);
        acc2[n] = __builtin_amdgcn_mfma_f32_16x16x32_bf16(ahi, whi, acc2[n], 0, 0, 0);
        acc2[n] = __builtin_amdgcn_mfma_f32_16x16x32_bf16(alo, whi, acc2[n], 0, 0, 0);
        acc2[n] = __builtin_amdgcn_mfma_f32_16x16x32_bf16(ahi, wlo, acc2[n], 0, 0, 0);
      }
    }
    __syncthreads();   // protect Ahi/htile before next segment overwrites
  };

  do_segment(image,  512, 512, 16, 0,  bi, 0);
  do_segment(tweets, 768, 768, 24, 16, bt, 1);
  do_segment(nump,   16,  16,  1,  40, bn, 2);
  do_segment(catg,   8,   8,   1,  41, bc, 3);

  const int rb  = m0 + w * 16 + (l >> 4) * 4;
  const int c15 = l & 15;
#pragma unroll
  for (int n = 0; n < 4; n++) {
    const int c = n * 16 + c15;
    const float bb = bf[c];
#pragma unroll
    for (int j = 0; j < 4; j++) {
      const int r = rb + j;
      if (r < M) nf[(size_t)r * 64 + c] = fmaxf(acc2[n][j] + bb, 0.f);
    }
  }
}

// ---------------------------------------------------------------------------
// Edge tables via MFMA. blocks [0,gT): Atab (Eet[:,:64], Wm1A, +bm1)
//                       blocks [gT,2gT): Btab (Eet[:,64:], Wm1B)
// Tab[r=n*3+t, :] = relu(nf[n] + Eet[t, half]) @ Wm1half (+ bm1 if A)
// ---------------------------------------------------------------------------
__global__ __launch_bounds__(256) void table_kernel(
    const float* __restrict__ nf, const float* __restrict__ Eet,
    const short* __restrict__ Whi, const short* __restrict__ Wlo,
    const float* __restrict__ bm1,
    float* __restrict__ Atab, float* __restrict__ Btab, int N3, int gT)
{
  const bool isB    = (int)blockIdx.x >= gT;
  const int  m0     = (isB ? (int)blockIdx.x - gT : (int)blockIdx.x) * 64;
  const int  eoff   = isB ? 64 : 0;
  const int  wstep0 = isB ? 52 : 50;
  float*     Tab    = isB ? Btab : Atab;

  __shared__ short Ahi[2][2048];
  __shared__ short Alo[2][2048];
  const int tid  = threadIdx.x;
  const int w    = tid >> 6, l = tid & 63;
  const int srow = tid >> 3;
  const int k0   = (tid & 7) * 4;
  const int i0   = k0 & 7;
  const int kg   = k0 >> 3;

#pragma unroll
  for (int ks2 = 0; ks2 < 2; ks2++) {
#pragma unroll
    for (int r2 = 0; r2 < 2; r2++) {
      const int row = srow + r2 * 32;
      const int rg  = m0 + row;
      float4 v = make_float4(0.f, 0.f, 0.f, 0.f);
      if (rg < N3) {
        const int n = rg / 3;
        const int t = rg - n * 3;
        const int k = ks2 * 32 + k0;
        float4 x = *reinterpret_cast<const float4*>(&nf[(size_t)n * 64 + k]);
        float4 e = *reinterpret_cast<const float4*>(&Eet[(size_t)t * 128 + eoff + k]);
        v.x = fmaxf(x.x + e.x, 0.f); v.y = fmaxf(x.y + e.y, 0.f);
        v.z = fmaxf(x.z + e.z, 0.f); v.w = fmaxf(x.w + e.w, 0.f);
      }
      uint2 hp, lp; split4(v, hp, lp);
      const int addr = (row >> 4) * 512 + (((row & 15) | (kg << 4)) * 8 + i0);
      *reinterpret_cast<uint2*>(&Ahi[ks2][addr]) = hp;
      *reinterpret_cast<uint2*>(&Alo[ks2][addr]) = lp;
    }
  }
  __syncthreads();

  f32x4 acc[4];
#pragma unroll
  for (int n = 0; n < 4; n++) acc[n] = (f32x4){0.f, 0.f, 0.f, 0.f};

#pragma unroll
  for (int ks2 = 0; ks2 < 2; ks2++) {
    short8 ahi = *reinterpret_cast<const short8*>(&Ahi[ks2][w * 512 + l * 8]);
    short8 alo = *reinterpret_cast<const short8*>(&Alo[ks2][w * 512 + l * 8]);
#pragma unroll
    for (int n = 0; n < 4; n++) {
      short8 whi = *reinterpret_cast<const short8*>(&Whi[((size_t)(wstep0 + ks2) * 4 + n) * 512 + l * 8]);
      short8 wlo = *reinterpret_cast<const short8*>(&Wlo[((size_t)(wstep0 + ks2) * 4 + n) * 512 + l * 8]);
      acc[n] = __builtin_amdgcn_mfma_f32_16x16x32_bf16(ahi, whi, acc[n], 0, 0, 0);
      acc[n] = __builtin_amdgcn_mfma_f32_16x16x32_bf16(alo, whi, acc[n], 0, 0, 0);
      acc[n] = __builtin_amdgcn_mfma_f32_16x16x32_bf16(ahi, wlo, acc[n], 0, 0, 0);
    }
  }

  const int rb  = m0 + w * 16 + (l >> 4) * 4;
  const int c15 = l & 15;
#pragma unroll
  for (int n = 0; n < 4; n++) {
    const int c = n * 16 + c15;
    const float bb = isB ? 0.f : bm1[c];
#pragma unroll
    for (int j = 0; j < 4; j++) {
      const int r = rb + j;
      if (r < N3) Tab[(size_t)r * 64 + c] = acc[n][j] + bb;
    }
  }
}

// ---------------------------------------------------------------------------
// 16 lanes per edge: logits -> sigmoid -> Bernoulli(u) -> trusted edges
// appended to per-src linked list (4B atomicExch + 4B store). No f32 atomics.
// ---------------------------------------------------------------------------
__global__ __launch_bounds__(256) void edge_kernel(
    const int* __restrict__ ei, const int* __restrict__ et,
    const float* __restrict__ u,
    const float* __restrict__ Atab, const float* __restrict__ Btab,
    const float* __restrict__ Wm2, const float* __restrict__ bm2,
    int* __restrict__ head, int* __restrict__ nxt, int E)
{
  const int tid = threadIdx.x;
  const int e   = blockIdx.x * 16 + (tid >> 4);
  const int sub = tid & 15;
  if (e >= E) return;

  const int sn = ei[e];
  const int dn = ei[E + e];
  const int t  = et[e];

  float4 a  = *reinterpret_cast<const float4*>(Atab + ((size_t)sn * 3 + t) * 64 + sub * 4);
  float4 b  = *reinterpret_cast<const float4*>(Btab + ((size_t)dn * 3 + t) * 64 + sub * 4);
  float4 wv = *reinterpret_cast<const float4*>(Wm2 + sub * 4);

  float v = fmaxf(a.x + b.x, 0.f) * wv.x;
  v = fmaf(fmaxf(a.y + b.y, 0.f), wv.y, v);
  v = fmaf(fmaxf(a.z + b.z, 0.f), wv.z, v);
  v = fmaf(fmaxf(a.w + b.w, 0.f), wv.w, v);
  v += __shfl_xor(v, 1);
  v += __shfl_xor(v, 2);
  v += __shfl_xor(v, 4);
  v += __shfl_xor(v, 8);

  if (sub == 0) {
    const float p = 1.f / (1.f + expf(-(v + bm2[0])));
    if (u[e] < p) {
      nxt[e] = atomicExch(&head[sn], e);
    }
  }
}

// ---------------------------------------------------------------------------
// one wave per node: walk trusted-edge chain, accumulate nf[dst] rows in
// DOUBLE (order-independent to f32 rounding), then agg @ Wcls + bcls -> out.
// ---------------------------------------------------------------------------
__global__ __launch_bounds__(256) void node_kernel(
    const int* __restrict__ head, const int* __restrict__ nxt,
    const int* __restrict__ ei,
    const float* __restrict__ nf,
    const float* __restrict__ Wcls, const float* __restrict__ bcls,
    float* __restrict__ out, int N, int E)
{
  const int n    = (int)((blockIdx.x * (unsigned)blockDim.x + threadIdx.x) >> 6);
  const int lane = threadIdx.x & 63;
  if (n >= N) return;

  double acc = 0.0;
  int    c   = 0;
  int    e   = head[n];
  while (e >= 0) {
    const int dn = ei[E + e];
    acc += (double)nf[(size_t)dn * 64 + lane];
    c++;
    e = nxt[e];
  }

  const float agg = (c > 0) ? (float)(acc / (double)c) : nf[(size_t)n * 64 + lane];
  float r0 = agg * Wcls[lane * 2 + 0];
  float r1 = agg * Wcls[lane * 2 + 1];
#pragma unroll
  for (int off = 32; off; off >>= 1) {
    r0 += __shfl_xor(r0, off, 64);
    r1 += __shfl_xor(r1, off, 64);
  }
  if (lane == 0) {
    out[(size_t)n * 2 + 0] = r0 + bcls[0];
    out[(size_t)n * 2 + 1] = r1 + bcls[1];
  }
}

// ---------------------------------------------------------------------------
extern "C" void kernel_launch(void* const* d_in, const int* in_sizes, int n_in,
                              void* d_out, int out_size, void* d_ws, size_t ws_size,
                              hipStream_t stream)
{
  const float* image    = (const float*)d_in[0];
  const float* tweets   = (const float*)d_in[1];
  const float* num_prop = (const float*)d_in[2];
  const float* category = (const float*)d_in[3];
  const int*   ei       = (const int*)  d_in[4];
  const int*   et       = (const int*)  d_in[5];
  // d_in[6] = eps : unused (z is dead code)
  const float* u        = (const float*)d_in[7];
  const float* Wi  = (const float*)d_in[8],  *bi  = (const float*)d_in[9];
  const float* Wt  = (const float*)d_in[10], *bt  = (const float*)d_in[11];
  const float* Wn  = (const float*)d_in[12], *bn  = (const float*)d_in[13];
  const float* Wc  = (const float*)d_in[14], *bc  = (const float*)d_in[15];
  const float* Wf  = (const float*)d_in[16], *bf  = (const float*)d_in[17];
  const float* Eet = (const float*)d_in[18];
  // d_in[19..22] = Wmu,bmu,Wlv,blv : unused (z is dead code)
  const float* Wm1 = (const float*)d_in[23], *bm1 = (const float*)d_in[24];
  const float* Wm2 = (const float*)d_in[25], *bm2 = (const float*)d_in[26];
  const float* Wcls= (const float*)d_in[27], *bcls= (const float*)d_in[28];
  float* out = (float*)d_out;

  const int N = in_sizes[0] / 512;
  const int E = in_sizes[5];

  float* ws = (float*)d_ws;
  size_t off = 0;
  float* nf     = ws + off;  off += (size_t)N * 64;
  float* Atab   = ws + off;  off += (size_t)N * 3 * 64;
  float* Btab   = ws + off;  off += (size_t)N * 3 * 64;
  int*   head   = (int*)(ws + off);  off += (size_t)N;
  int*   nxt    = (int*)(ws + off);  off += (size_t)E;
  short* Wfhi   = (short*)(ws + off);  off += (1728 * 64) / 2;
  short* Wflo   = (short*)(ws + off);  off += (1728 * 64) / 2;

  init_head<<<(N + 255) / 256, 256, 0, stream>>>(head, N);

  prep_w<<<(1728 * 64 + 255) / 256, 256, 0, stream>>>(Wi, Wt, Wn, Wc, Wf, Wm1,
                                                      Wfhi, Wflo);

  const int gN = (N + 63) / 64;
  encoder<<<gN, 256, 0, stream>>>(image, tweets, num_prop, category,
                                  Wfhi, Wflo, bi, bt, bn, bc, bf, nf, N);

  const int N3 = N * 3;
  const int gT = (N3 + 63) / 64;
  table_kernel<<<2 * gT, 256, 0, stream>>>(nf, Eet, Wfhi, Wflo, bm1,
                                           Atab, Btab, N3, gT);

  edge_kernel<<<(E + 15) / 16, 256, 0, stream>>>(ei, et, u, Atab, Btab,
                                                 Wm2, bm2, head, nxt, E);

  node_kernel<<<(N + 3) / 4, 256, 0, stream>>>(head, nxt, ei, nf, Wcls, bcls,
                                               out, N, E);
}